// Round 2
// baseline (90.125 us; speedup 1.0000x reference)
//
#include <hip/hip_runtime.h>

#define B_ 256
#define K_ 512
#define D_ 64
#define KD_ 576   // K + D
#define LOG2E 1.44269504088896340736f

typedef float v2f __attribute__((ext_vector_type(2)));

__device__ __forceinline__ float fexp2(float x) {
#if __has_builtin(__builtin_amdgcn_exp2f)
    return __builtin_amdgcn_exp2f(x);
#else
    float r; asm("v_exp_f32 %0, %1" : "=v"(r) : "v"(x)); return r;
#endif
}
__device__ __forceinline__ float frcp(float x) {
#if __has_builtin(__builtin_amdgcn_rcpf)
    return __builtin_amdgcn_rcpf(x);
#else
    float r; asm("v_rcp_f32 %0, %1" : "=v"(r) : "v"(x)); return r;
#endif
}
__device__ __forceinline__ float fsig(float x) {
    return frcp(1.0f + fexp2(-LOG2E * x));
}

// ---------------------------------------------------------------------------
// K1 "prep": S1,S2 (B x K) and F1,F2 (K x K), all via 32x32 LDS-tiled dots
// over D=64. Also zeroes the 64 finisher counters (block 0).
// grid: 640 blocks x 256. bid<128 -> S-part (bt=bid>>4, nt=bid&15);
// else q=bid-128: mat=q>>8, kt=(q>>4)&15, nt=q&15.
// ---------------------------------------------------------------------------
__global__ void __launch_bounds__(256) kPrep(const int* __restrict__ sid,
                                             const int* __restrict__ eid,
                                             const float* __restrict__ stu_t,
                                             const float* __restrict__ exer_t,
                                             const float* __restrict__ kn_t,
                                             const float* __restrict__ W1,
                                             const float* __restrict__ W2,
                                             float* __restrict__ S1,
                                             float* __restrict__ S2,
                                             float* __restrict__ F1,
                                             float* __restrict__ F2,
                                             unsigned* __restrict__ cnt) {
    __shared__ float At[2][32][65];
    __shared__ float Bt[32][65];
    __shared__ int ids[64];
    const int t = threadIdx.x;
    const int bid = blockIdx.x;
    if (bid == 0 && t < 64) cnt[t] = 0u;

    if (bid < 128) {
        // ---- S-part: S[b,n] = sigmoid(gathered_row[b] . kn[n]) for stu & exer
        const int b0 = (bid >> 4) * 32;
        const int n0 = (bid & 15) * 32;
        if (t < 32) ids[t] = sid[b0 + t];
        else if (t < 64) ids[t] = eid[b0 + t - 32];
        __syncthreads();
        for (int idx = t; idx < 2048; idx += 256) {
            const int r = idx >> 6, d = idx & 63;
            At[0][r][d] = stu_t[(size_t)ids[r] * D_ + d];
            At[1][r][d] = exer_t[(size_t)ids[32 + r] * D_ + d];
            Bt[r][d]    = kn_t[(size_t)(n0 + r) * D_ + d];
        }
        __syncthreads();
        const int nl = 2 * (t & 15);   // n-local (coalesced writes)
        const int il = 2 * (t >> 4);   // b-local
        float acc[2][2][2] = {};
#pragma unroll 8
        for (int d = 0; d < 64; d++) {
            const float bv0 = Bt[nl][d], bv1 = Bt[nl + 1][d];
#pragma unroll
            for (int tab = 0; tab < 2; tab++)
#pragma unroll
                for (int x = 0; x < 2; x++) {
                    const float av = At[tab][il + x][d];
                    acc[tab][x][0] = fmaf(av, bv0, acc[tab][x][0]);
                    acc[tab][x][1] = fmaf(av, bv1, acc[tab][x][1]);
                }
        }
#pragma unroll
        for (int x = 0; x < 2; x++)
#pragma unroll
            for (int y = 0; y < 2; y++) {
                S1[(size_t)(b0 + il + x) * K_ + n0 + nl + y] = fsig(acc[0][x][y]);
                S2[(size_t)(b0 + il + x) * K_ + n0 + nl + y] = fsig(acc[1][x][y]);
            }
    } else {
        // ---- F-part: F[k,n] = exp(-(kn[k] . W[n, K:K+D]))
        const int q = bid - 128;
        const int mat = q >> 8;
        const int k0 = ((q >> 4) & 15) * 32;
        const int n0 = (q & 15) * 32;
        const float* W = mat ? W2 : W1;
        float* F = mat ? F2 : F1;
        for (int idx = t; idx < 2048; idx += 256) {
            const int r = idx >> 6, d = idx & 63;
            At[0][r][d] = kn_t[(size_t)(k0 + r) * D_ + d];
            Bt[r][d]    = W[(size_t)(n0 + r) * KD_ + K_ + d];
        }
        __syncthreads();
        const int nl = 2 * (t & 15);
        const int kl = 2 * (t >> 4);
        float acc[2][2] = {};
#pragma unroll 8
        for (int d = 0; d < 64; d++) {
            const float bv0 = Bt[nl][d], bv1 = Bt[nl + 1][d];
#pragma unroll
            for (int x = 0; x < 2; x++) {
                const float av = At[0][kl + x][d];
                acc[x][0] = fmaf(av, bv0, acc[x][0]);
                acc[x][1] = fmaf(av, bv1, acc[x][1]);
            }
        }
#pragma unroll
        for (int x = 0; x < 2; x++)
#pragma unroll
            for (int y = 0; y < 2; y++)
                F[(size_t)(k0 + kl + x) * K_ + n0 + nl + y] = fexp2(-LOG2E * acc[x][y]);
    }
}

// ---------------------------------------------------------------------------
// K2 "E-stage": A-partials. Ah[(half*2+mat)][b][m] = sum_{k in half} S[b,k]*W[m,k]
// Tiled GEMM: 32b x 32m tile, k-half = 256 in chunks of 64. grid (16,8,4).
// ---------------------------------------------------------------------------
__global__ void __launch_bounds__(256) kE(const float* __restrict__ Sbase,
                                          const float* __restrict__ W1,
                                          const float* __restrict__ W2,
                                          float* __restrict__ Ah) {
    __shared__ float Sm[32][65];
    __shared__ float Wm[32][65];
    const int t = threadIdx.x;
    const int m0 = blockIdx.x * 32;
    const int b0 = blockIdx.y * 32;
    const int mat = blockIdx.z >> 1;
    const int half = blockIdx.z & 1;
    const int k0 = half * 256;
    const float* S = Sbase + (size_t)mat * (B_ * K_);
    const float* W = mat ? W2 : W1;
    const int ml = 2 * (t & 15);
    const int bl = 2 * (t >> 4);
    float acc[2][2] = {};
    for (int kc = 0; kc < 4; kc++) {
        __syncthreads();
        for (int idx = t; idx < 2048; idx += 256) {
            const int r = idx >> 6, d = idx & 63;
            Sm[r][d] = S[(size_t)(b0 + r) * K_ + k0 + kc * 64 + d];
            Wm[r][d] = W[(size_t)(m0 + r) * KD_ + k0 + kc * 64 + d];
        }
        __syncthreads();
#pragma unroll 8
        for (int d = 0; d < 64; d++) {
            const float w0 = Wm[ml][d], w1 = Wm[ml + 1][d];
            const float s0 = Sm[bl][d], s1 = Sm[bl + 1][d];
            acc[0][0] = fmaf(s0, w0, acc[0][0]);
            acc[0][1] = fmaf(s0, w1, acc[0][1]);
            acc[1][0] = fmaf(s1, w0, acc[1][0]);
            acc[1][1] = fmaf(s1, w1, acc[1][1]);
        }
    }
    float* Ao = Ah + (size_t)(half * 2 + mat) * (B_ * K_);
#pragma unroll
    for (int x = 0; x < 2; x++)
#pragma unroll
        for (int y = 0; y < 2; y++)
            Ao[(size_t)(b0 + bl + x) * K_ + m0 + ml + y] = acc[x][y];
}

// ---------------------------------------------------------------------------
// K3 "main": per (b,k): t = sum_m ((qd-pd)/(pd*qd)) * W3[m], pd=1+E1*F1, qd=1+E2*F2.
// E combined from A-halves + exp'd once into LDS per block. Packed f32 math,
// 1 rcp per pair. Last-arriving block per b-group does the final reduce.
// grid (16, 64), block 256 (4 waves; wave w -> 8 k's).
// ---------------------------------------------------------------------------
__global__ void __launch_bounds__(256) kMain(const float* __restrict__ Ah,
                                             const float* __restrict__ F1,
                                             const float* __restrict__ F2,
                                             const float* __restrict__ W3,
                                             const float* __restrict__ b3,
                                             const float* __restrict__ kn_emb,
                                             float* __restrict__ partial,
                                             unsigned* __restrict__ cnt,
                                             float* __restrict__ out) {
    __shared__ float elds[2][4][512];   // 16 KB: e = exp(-(A_h0+A_h1)), per mat x bi x n
    __shared__ int sdone;
    const int t = threadIdx.x;
    const int lane = t & 63;
    const int wave = t >> 6;
    const int b0 = blockIdx.y * 4;
    const int kbase = blockIdx.x * 32 + wave * 8;

    for (int idx = t; idx < 4096; idx += 256) {
        const int mat = idx >> 11, bi = (idx >> 9) & 3, n = idx & 511;
        const float a0 = Ah[((size_t)(0 * 2 + mat) * B_ + b0 + bi) * K_ + n];
        const float a1 = Ah[((size_t)(1 * 2 + mat) * B_ + b0 + bi) * K_ + n];
        elds[mat][bi][n] = fexp2(-LOG2E * (a0 + a1));
    }
    __syncthreads();

    v2f e1v[4][4], e2v[4][4], w3v[4];
#pragma unroll
    for (int c = 0; c < 4; c++) {
        const int n = c * 128 + lane * 2;
        w3v[c] = *(const v2f*)&W3[n];
#pragma unroll
        for (int bi = 0; bi < 4; bi++) {
            e1v[bi][c] = *(const v2f*)&elds[0][bi][n];
            e2v[bi][c] = *(const v2f*)&elds[1][bi][n];
        }
    }
    const float b3v = b3[0];
    const v2f one = {1.0f, 1.0f};
    float sum[4] = {0.f, 0.f, 0.f, 0.f};

    for (int kk = 0; kk < 8; kk++) {
        const int k = kbase + kk;
        const float* f1r = F1 + (size_t)k * K_;
        const float* f2r = F2 + (size_t)k * K_;
        v2f tv[4];
#pragma unroll
        for (int bi = 0; bi < 4; bi++) { tv[bi].x = 0.f; tv[bi].y = 0.f; }
#pragma unroll
        for (int c = 0; c < 4; c++) {
            const v2f f1 = *(const v2f*)&f1r[c * 128 + lane * 2];
            const v2f f2 = *(const v2f*)&f2r[c * 128 + lane * 2];
#pragma unroll
            for (int bi = 0; bi < 4; bi++) {
                const v2f pd = e1v[bi][c] * f1 + one;
                const v2f qd = e2v[bi][c] * f2 + one;
                const v2f num = qd - pd;
                const v2f den = pd * qd;
                v2f r; r.x = frcp(den.x); r.y = frcp(den.y);
                tv[bi] += num * r * w3v[c];
            }
        }
#pragma unroll
        for (int bi = 0; bi < 4; bi++) {
            float s = tv[bi].x + tv[bi].y;
#pragma unroll
            for (int off = 32; off; off >>= 1) s += __shfl_xor(s, off, 64);
            const float o = fsig(s + b3v);
            sum[bi] = fmaf(o, kn_emb[(size_t)(b0 + bi) * K_ + k], sum[bi]);
        }
    }
    if (lane == 0) {
        const int col = blockIdx.x * 4 + wave;  // 0..63
#pragma unroll
        for (int bi = 0; bi < 4; bi++)
            partial[(size_t)(b0 + bi) * 64 + col] = sum[bi];
    }
    __syncthreads();   // drains all waves' stores (vmcnt(0)) before signaling
    if (t == 0) {
        __threadfence();                       // device-scope release
        const unsigned old = atomicAdd(&cnt[blockIdx.y], 1u);
        sdone = (old == 15u) ? 1 : 0;
    }
    __syncthreads();
    if (sdone && t < 64) {
        __threadfence();                       // device-scope acquire
#pragma unroll
        for (int bi = 0; bi < 4; bi++) {
            float num = partial[(size_t)(b0 + bi) * 64 + t];
            float den = 0.f;
#pragma unroll
            for (int c = 0; c < 8; c++) den += kn_emb[(size_t)(b0 + bi) * K_ + c * 64 + t];
#pragma unroll
            for (int off = 32; off; off >>= 1) {
                num += __shfl_xor(num, off, 64);
                den += __shfl_xor(den, off, 64);
            }
            if (t == 0) out[b0 + bi] = num / den;
        }
    }
}

extern "C" void kernel_launch(void* const* d_in, const int* in_sizes, int n_in,
                              void* d_out, int out_size, void* d_ws, size_t ws_size,
                              hipStream_t stream) {
    const int*   stu_id     = (const int*)d_in[0];
    const int*   exer_id    = (const int*)d_in[1];
    const float* kn_emb     = (const float*)d_in[2];
    const float* stu_table  = (const float*)d_in[3];
    const float* exer_table = (const float*)d_in[4];
    const float* kn_table   = (const float*)d_in[5];
    const float* W1         = (const float*)d_in[6];
    const float* W2         = (const float*)d_in[7];
    const float* W3         = (const float*)d_in[8];
    const float* b3         = (const float*)d_in[9];
    float* out = (float*)d_out;

    float* ws      = (float*)d_ws;
    float* S1      = ws;                          // B*K
    float* S2      = ws + (size_t)B_ * K_;        // B*K
    float* F1      = ws + 2 * (size_t)B_ * K_;    // K*K
    float* F2      = F1 + (size_t)K_ * K_;        // K*K
    float* Ah      = F2 + (size_t)K_ * K_;        // 4 * B*K  (half x mat)
    float* partial = Ah + 4 * (size_t)B_ * K_;    // B*64
    unsigned* cnt  = (unsigned*)(partial + (size_t)B_ * 64);  // 64

    kPrep<<<640, 256, 0, stream>>>(stu_id, exer_id, stu_table, exer_table,
                                   kn_table, W1, W2, S1, S2, F1, F2, cnt);
    kE<<<dim3(16, 8, 4), 256, 0, stream>>>(S1, W1, W2, Ah);
    kMain<<<dim3(16, 64), 256, 0, stream>>>(Ah, F1, F2, W3, b3, kn_emb,
                                            partial, cnt, out);
}

// Round 3
// 77.510 us; speedup vs baseline: 1.1628x; 1.1628x over previous
//
#include <hip/hip_runtime.h>

#define B_ 256
#define K_ 512
#define D_ 64
#define KD_ 576
#define LOG2E 1.44269504088896340736f

typedef float v4f __attribute__((ext_vector_type(4)));
typedef short bf16x8 __attribute__((ext_vector_type(8)));
typedef float f32x16 __attribute__((ext_vector_type(16)));

#define ZERO16 {0.f,0.f,0.f,0.f,0.f,0.f,0.f,0.f,0.f,0.f,0.f,0.f,0.f,0.f,0.f,0.f}

__device__ __forceinline__ float fexp2(float x) {
#if __has_builtin(__builtin_amdgcn_exp2f)
    return __builtin_amdgcn_exp2f(x);
#else
    float r; asm("v_exp_f32 %0, %1" : "=v"(r) : "v"(x)); return r;
#endif
}
__device__ __forceinline__ float frcp(float x) {
#if __has_builtin(__builtin_amdgcn_rcpf)
    return __builtin_amdgcn_rcpf(x);
#else
    float r; asm("v_rcp_f32 %0, %1" : "=v"(r) : "v"(x)); return r;
#endif
}
__device__ __forceinline__ float fsig(float x) {
    return frcp(1.0f + fexp2(-LOG2E * x));
}
__device__ __forceinline__ ushort f2bf(float f) {
    union { float f; unsigned u; } v; v.f = f;
    return (ushort)((v.u + 0x7FFFu + ((v.u >> 16) & 1u)) >> 16);
}
__device__ __forceinline__ bf16x8 ldcvt8(const float* p) {
    float4 a = *(const float4*)p;
    float4 b = *(const float4*)(p + 4);
    bf16x8 r;
    r[0] = (short)f2bf(a.x); r[1] = (short)f2bf(a.y);
    r[2] = (short)f2bf(a.z); r[3] = (short)f2bf(a.w);
    r[4] = (short)f2bf(b.x); r[5] = (short)f2bf(b.y);
    r[6] = (short)f2bf(b.z); r[7] = (short)f2bf(b.w);
    return r;
}
__device__ __forceinline__ void gl_lds16(const void* g, void* l3) {
    __builtin_amdgcn_global_load_lds(
        (const __attribute__((address_space(1))) unsigned int*)g,
        (__attribute__((address_space(3))) unsigned int*)l3, 16, 0, 0);
}

// ---------------------------------------------------------------------------
// kPrep (256 blocks x 256 thr), three segments:
//  [0,64):   Sb[tab][b][n] = bf16(sigmoid(table_row[b] . kn[n]))   MFMA, D=64
//  [64,192): F[mat][k][n]  = exp(-(kn[k] . W[n, K:K+D]))  f32      MFMA, D=64
//  [192,256): Wkb[mat][m][0:K] = bf16(W[m][0:K]); block 192 zeroes cnt
// ---------------------------------------------------------------------------
__global__ void __launch_bounds__(256) kPrep(const int* __restrict__ sid,
                                             const int* __restrict__ eid,
                                             const float* __restrict__ stu_t,
                                             const float* __restrict__ exer_t,
                                             const float* __restrict__ kn_t,
                                             const float* __restrict__ W1,
                                             const float* __restrict__ W2,
                                             ushort* __restrict__ Sbu,
                                             ushort* __restrict__ Wkbu,
                                             float* __restrict__ F1,
                                             float* __restrict__ F2,
                                             unsigned* __restrict__ cnt) {
    const int bid = blockIdx.x, t = threadIdx.x;
    const int l = t & 63, w = t >> 6;
    const int dk = (l >> 5) * 8;
    if (bid < 64) {
        const int tab = bid >> 5, bt = (bid >> 3) & 3, nt = bid & 7;
        const int b0 = bt * 64, n0 = nt * 64;
        const int brow = b0 + (w & 1) * 32 + (l & 31);
        const int ncol = n0 + (w >> 1) * 32 + (l & 31);
        const int id = (tab ? eid : sid)[brow];
        const float* ar = (tab ? exer_t : stu_t) + (size_t)id * D_;
        const float* br = kn_t + (size_t)ncol * D_;
        f32x16 acc = ZERO16;
#pragma unroll
        for (int kk = 0; kk < 4; kk++) {
            bf16x8 a = ldcvt8(ar + kk * 16 + dk);
            bf16x8 b = ldcvt8(br + kk * 16 + dk);
            acc = __builtin_amdgcn_mfma_f32_32x32x16_bf16(a, b, acc, 0, 0, 0);
        }
        ushort* So = Sbu + (size_t)tab * B_ * K_;
#pragma unroll
        for (int r = 0; r < 16; r++) {
            const int row = (r & 3) + 8 * (r >> 2) + 4 * (l >> 5);
            So[(size_t)(b0 + (w & 1) * 32 + row) * K_ + ncol] = f2bf(fsig(acc[r]));
        }
    } else if (bid < 192) {
        const int fid = bid - 64;
        const int mat = fid >> 6, kt = (fid >> 3) & 7, nt = fid & 7;
        const int k0 = kt * 64, n0 = nt * 64;
        const int krow = k0 + (w & 1) * 32 + (l & 31);
        const int ncol = n0 + (w >> 1) * 32 + (l & 31);
        const float* Wm = mat ? W2 : W1;
        const float* ar = kn_t + (size_t)krow * D_;
        const float* br = Wm + (size_t)ncol * KD_ + K_;
        f32x16 acc = ZERO16;
#pragma unroll
        for (int kk = 0; kk < 4; kk++) {
            bf16x8 a = ldcvt8(ar + kk * 16 + dk);
            bf16x8 b = ldcvt8(br + kk * 16 + dk);
            acc = __builtin_amdgcn_mfma_f32_32x32x16_bf16(a, b, acc, 0, 0, 0);
        }
        float* Fo = mat ? F2 : F1;
#pragma unroll
        for (int r = 0; r < 16; r++) {
            const int row = (r & 3) + 8 * (r >> 2) + 4 * (l >> 5);
            Fo[(size_t)(k0 + (w & 1) * 32 + row) * K_ + ncol] = fexp2(-LOG2E * acc[r]);
        }
    } else {
        const int cid = bid - 192;  // 0..63
#pragma unroll
        for (int it = 0; it < 8; it++) {
            const int q = (((cid * 8 + it) * 256) + t) * 4;   // < 2*512*512
            const int mat = q >> 18, rm = (q >> 9) & 511, col = q & 511;
            const float* Wsrc = mat ? W2 : W1;
            float4 v = *(const float4*)(Wsrc + (size_t)rm * KD_ + col);
            ushort4 o = { f2bf(v.x), f2bf(v.y), f2bf(v.z), f2bf(v.w) };
            *(ushort4*)(Wkbu + q) = o;
        }
        if (cid == 0 && t < 64) cnt[t] = 0u;
    }
}

// ---------------------------------------------------------------------------
// kE (512 blocks x 256 thr): Ah[ks*2+mat][b][m] = sum_{k in ks-slice(64)} Sb[b,k]*Wkb[m,k]
// MFMA bf16, frags straight from global (L2).
// ---------------------------------------------------------------------------
__global__ void __launch_bounds__(256) kE(const ushort* __restrict__ Sbu,
                                          const ushort* __restrict__ Wkbu,
                                          float* __restrict__ Ah) {
    const int bid = blockIdx.x, t = threadIdx.x;
    const int l = t & 63, w = t >> 6;
    const int mt = bid & 7, bt = (bid >> 3) & 3, z = bid >> 5;   // z 0..15
    const int mat = z & 1, ks = z >> 1;                           // ks 0..7
    const int m0 = mt * 64, b0 = bt * 64;
    const int brow = b0 + (w >> 1) * 32 + (l & 31);
    const int mrow = m0 + (w & 1) * 32 + (l & 31);
    const int koff = ks * 64 + (l >> 5) * 8;
    const short* Sp = (const short*)Sbu + (size_t)(mat * B_ + brow) * K_ + koff;
    const short* Wp = (const short*)Wkbu + (size_t)(mat * K_ + mrow) * K_ + koff;
    f32x16 acc = ZERO16;
#pragma unroll
    for (int kk = 0; kk < 4; kk++) {
        bf16x8 a = *(const bf16x8*)(Sp + kk * 16);
        bf16x8 b = *(const bf16x8*)(Wp + kk * 16);
        acc = __builtin_amdgcn_mfma_f32_32x32x16_bf16(a, b, acc, 0, 0, 0);
    }
    float* Ao = Ah + (size_t)(ks * 2 + mat) * B_ * K_;
#pragma unroll
    for (int r = 0; r < 16; r++) {
        const int row = (r & 3) + 8 * (r >> 2) + 4 * (l >> 5);
        Ao[(size_t)(b0 + (w >> 1) * 32 + row) * K_ + mrow] = acc[r];
    }
}

// ---------------------------------------------------------------------------
// kMain: grid (4 kgroups, 64 bgroups), 512 thr (8 waves).
// Lane = (k,b): kl=l&15 (16 k's), bi=l>>4 (4 b's). krow = w*16+kl (128 k/block).
// F tiles (128k x 64n x 2mat) LDS double-buffered via global_load_lds with
// XOR-swizzled (per 16B unit) pre-swizzled global source; e/W3 broadcast.
// No cross-lane ops in the n-loop. Fused deterministic finisher.
// ---------------------------------------------------------------------------
__global__ void __launch_bounds__(512) kMain(const float* __restrict__ F1,
                                             const float* __restrict__ F2,
                                             const float* __restrict__ Ah,
                                             const float* __restrict__ W3,
                                             const float* __restrict__ b3,
                                             const float* __restrict__ kn_emb,
                                             float* __restrict__ partial,
                                             unsigned* __restrict__ cnt,
                                             float* __restrict__ out) {
    __shared__ float fs[32768];   // [buf2][mat2][k128][64f swizzled] = 128 KB
    __shared__ float es[4096];    // [bi4][mat2][n512] = 16 KB
    __shared__ float w3s[512];
    __shared__ float red[32];
    __shared__ int sdone;
    const int t = threadIdx.x;
    const int l = t & 63, w = t >> 6;
    const int kbase = blockIdx.x * 128;
    const int b0 = blockIdx.y * 4;

#define STAGE(CH, BUF) do {                                                     \
    const int n0s_ = (CH) * 64;                                                 \
    _Pragma("unroll")                                                           \
    for (int ii = 0; ii < 8; ii++) {                                            \
        const int m_ = w * 8 + ii;                                              \
        const int mat_ = m_ >> 5;                                               \
        const int j_ = m_ & 31;                                                 \
        const int k_ = j_ * 4 + (l >> 4);                                       \
        const int u_ = l & 15;                                                  \
        const float* g_ = (mat_ ? F2 : F1) + (size_t)(kbase + k_) * K_ + n0s_   \
                          + (((u_ ^ (k_ & 7)) << 2));                           \
        char* d_ = (char*)fs + (BUF) * 65536 + mat_ * 32768 + j_ * 1024;        \
        gl_lds16(g_, d_);                                                       \
    }                                                                           \
} while (0)

    STAGE(0, 0);

    // e-stage: es[bi][mat][n] = exp(-(sum over 8 ksplits of Ah))
    for (int i = t; i < 4096; i += 512) {
        const int n = i & 511, mat = (i >> 9) & 1, bi = i >> 10;
        float a = 0.f;
#pragma unroll
        for (int ks = 0; ks < 8; ks++)
            a += Ah[((size_t)(ks * 2 + mat) * B_ + b0 + bi) * K_ + n];
        es[(bi * 2 + mat) * 512 + n] = fexp2(-LOG2E * a);
    }
    w3s[t & 511] = W3[t & 511];
    const float b3v = b3[0];

    const int kl = l & 15, bi = l >> 4;
    const int krow = w * 16 + kl;
    const int swz = (kl & 7) << 2;
    const float* e1p = es + (size_t)bi * 1024;
    const float* e2p = e1p + 512;

    __syncthreads();

    v4f acc0 = {0.f, 0.f, 0.f, 0.f};
    v4f acc1 = {0.f, 0.f, 0.f, 0.f};

    for (int c = 0; c < 8; c++) {
        const int buf = c & 1;
        if (c < 7) STAGE(c + 1, buf ^ 1);
        const int n0 = c * 64;
        const float* fp1 = fs + buf * 16384 + krow * 64;
        const float* fp2 = fp1 + 8192;
        const float* e1c = e1p + n0;
        const float* e2c = e2p + n0;
        const float* w3c = w3s + n0;
#pragma unroll 8
        for (int u = 0; u < 16; u++) {
            const int off = (u << 2) ^ swz;
            v4f f1 = *(const v4f*)(fp1 + off);
            v4f f2 = *(const v4f*)(fp2 + off);
            v4f e1 = *(const v4f*)(e1c + 4 * u);
            v4f e2 = *(const v4f*)(e2c + 4 * u);
            v4f w3 = *(const v4f*)(w3c + 4 * u);
            v4f pd = e1 * f1 + 1.0f;
            v4f qd = e2 * f2 + 1.0f;
            v4f num = qd - pd;
            v4f den = pd * qd;
            v4f r;
            r.x = frcp(den.x); r.y = frcp(den.y);
            r.z = frcp(den.z); r.w = frcp(den.w);
            if (u & 1) acc1 += (num * r) * w3;
            else       acc0 += (num * r) * w3;
        }
        __syncthreads();
    }

    v4f accv = acc0 + acc1;
    const float s = accv.x + accv.y + accv.z + accv.w;
    const float o = fsig(s + b3v);
    float g = o * kn_emb[(size_t)(b0 + bi) * K_ + kbase + krow];
    g += __shfl_xor(g, 1, 64);
    g += __shfl_xor(g, 2, 64);
    g += __shfl_xor(g, 4, 64);
    g += __shfl_xor(g, 8, 64);
    if (kl == 0) red[w * 4 + bi] = g;
    __syncthreads();
    if (t < 4) {
        float v = 0.f;
#pragma unroll
        for (int ww = 0; ww < 8; ww++) v += red[ww * 4 + t];
        __hip_atomic_store(&partial[(size_t)(b0 + t) * 4 + blockIdx.x], v,
                           __ATOMIC_RELEASE, __HIP_MEMORY_SCOPE_AGENT);
    }
    __syncthreads();
    if (t == 0) {
        const unsigned old = __hip_atomic_fetch_add(&cnt[blockIdx.y], 1u,
                             __ATOMIC_ACQ_REL, __HIP_MEMORY_SCOPE_AGENT);
        sdone = (old == 3u) ? 1 : 0;
    }
    __syncthreads();
    if (sdone && t < 256) {
        const int bi2 = t >> 6, ll = t & 63;
        float den = 0.f;
#pragma unroll
        for (int c2 = 0; c2 < 8; c2++)
            den += kn_emb[(size_t)(b0 + bi2) * K_ + c2 * 64 + ll];
#pragma unroll
        for (int off = 32; off; off >>= 1) den += __shfl_xor(den, off, 64);
        if (ll == 0) {
            float num = 0.f;
#pragma unroll
            for (int kg = 0; kg < 4; kg++)
                num += __hip_atomic_load(&partial[(size_t)(b0 + bi2) * 4 + kg],
                                         __ATOMIC_ACQUIRE, __HIP_MEMORY_SCOPE_AGENT);
            out[b0 + bi2] = num / den;
        }
    }
#undef STAGE
}

extern "C" void kernel_launch(void* const* d_in, const int* in_sizes, int n_in,
                              void* d_out, int out_size, void* d_ws, size_t ws_size,
                              hipStream_t stream) {
    const int*   stu_id     = (const int*)d_in[0];
    const int*   exer_id    = (const int*)d_in[1];
    const float* kn_emb     = (const float*)d_in[2];
    const float* stu_table  = (const float*)d_in[3];
    const float* exer_table = (const float*)d_in[4];
    const float* kn_table   = (const float*)d_in[5];
    const float* W1         = (const float*)d_in[6];
    const float* W2         = (const float*)d_in[7];
    const float* W3         = (const float*)d_in[8];
    const float* b3         = (const float*)d_in[9];
    float* out = (float*)d_out;

    float* ws = (float*)d_ws;
    float* F1       = ws;                                   // 262144 f
    float* F2       = F1 + (size_t)K_ * K_;                 // 262144 f
    float* Ah       = F2 + (size_t)K_ * K_;                 // 16 * B*K f = 8 MB
    ushort* Sbu     = (ushort*)(Ah + (size_t)16 * B_ * K_); // 262144 us
    ushort* Wkbu    = Sbu + (size_t)2 * B_ * K_;            // 524288 us
    float* partial  = (float*)(Wkbu + (size_t)2 * K_ * K_); // 1024 f
    unsigned* cnt   = (unsigned*)(partial + 1024);          // 64

    kPrep<<<256, 256, 0, stream>>>(stu_id, exer_id, stu_table, exer_table,
                                   kn_table, W1, W2, Sbu, Wkbu, F1, F2, cnt);
    kE<<<512, 256, 0, stream>>>(Sbu, Wkbu, Ah);
    kMain<<<dim3(4, 64), 512, 0, stream>>>(F1, F2, Ah, W3, b3, kn_emb,
                                           partial, cnt, out);
}